// Round 9
// baseline (339.710 us; speedup 1.0000x reference)
//
#include <hip/hip_runtime.h>
#include <hip/hip_bf16.h>
#include <math.h>

#define BE   256
#define DIM  256
#define OUTD 128
#define LCL  256
#define LEV  512

#define NCH_EV 16              // 512/32 chunks per evidence pair
#define NCH_CL 8               // 256/32 chunks per claim pair
#define NCHP   (NCH_EV + NCH_CL)
#define NBLK   (BE * NCHP)     // 6144 chunk blocks

typedef short  bf16x8  __attribute__((ext_vector_type(8)));
typedef float  floatx4 __attribute__((ext_vector_type(4)));

union BF1 { __hip_bfloat16 h; unsigned short u; };
union BF2 { __hip_bfloat162 h; unsigned int u; };

__device__ __forceinline__ float fast_tanh(float x) {
    float xc = fminf(fmaxf(x, -15.f), 15.f);
    float e = __expf(2.f * xc);                       // e^{2x}
    return (e - 1.f) * __builtin_amdgcn_rcpf(e + 1.f);
}

__device__ __forceinline__ float4 f4add(float4 a, float4 b) {
    return make_float4(a.x + b.x, a.y + b.y, a.z + b.z, a.w + b.w);
}

// Direct global->LDS DMA, 16B per lane. Dest is wave-uniform base
// (HW writes lane i at base + i*16); source is per-lane.
__device__ __forceinline__ void gl_lds16(const float4* g, float4* l) {
    __builtin_amdgcn_global_load_lds(
        (const __attribute__((address_space(1))) unsigned int*)(const void*)g,
        (__attribute__((address_space(3))) unsigned int*)(void*)l,
        16, 0, 0);
}

// ---------------------------------------------------------------------------
// K1: mean partials, massively parallel streaming (pays the COLD HBM read).
// One block per 32-row chunk (same bid mapping as k_main). 256 thr: wave wv
// covers rows wv*8..+8; thread sums 8 INDEPENDENT float4 loads (named regs,
// tree sum -- R7's meanbias had 256 blocks + a serial chain => 1.15 TB/s).
// (256,4): 4 blocks/CU, 16 waves/CU, ~128KB in flight per CU.
// NOTE: writes `partial` which ALIASES O_part (disjoint live ranges:
// partial dies at k_redbias, O_part born at k_main) -- keeps workspace at
// R7's proven ~6.4 MB footprint (R8's +6.3 MB likely overran ws_size).
// ---------------------------------------------------------------------------
__global__ __launch_bounds__(256, 4) void k_meanpart(
    const float* __restrict__ claim, const float* __restrict__ evidence,
    float* __restrict__ partial)
{
    const int bid = blockIdx.x;
    const int pair = bid / NCHP;
    const int c = bid - pair * NCHP;
    const bool is_ev = c < NCH_EV;
    const int chunk = is_ev ? c : c - NCH_EV;
    const float* __restrict__ seq = is_ev ? evidence : claim;
    const int L = is_ev ? LEV : LCL;

    const int t = threadIdx.x;
    const int d4 = t & 63, wv = t >> 6;
    const float4* base = (const float4*)(seq + ((size_t)pair * L + chunk * 32) * DIM);

    float4 v0 = base[(wv * 8 + 0) * 64 + d4];
    float4 v1 = base[(wv * 8 + 1) * 64 + d4];
    float4 v2 = base[(wv * 8 + 2) * 64 + d4];
    float4 v3 = base[(wv * 8 + 3) * 64 + d4];
    float4 v4 = base[(wv * 8 + 4) * 64 + d4];
    float4 v5 = base[(wv * 8 + 5) * 64 + d4];
    float4 v6 = base[(wv * 8 + 6) * 64 + d4];
    float4 v7 = base[(wv * 8 + 7) * 64 + d4];
    const float4 s = f4add(f4add(f4add(v0, v1), f4add(v2, v3)),
                           f4add(f4add(v4, v5), f4add(v6, v7)));

    __shared__ float4 sm[4][64];
    sm[wv][d4] = s;
    __syncthreads();
    if (t < 64) {
        const float4 r = f4add(f4add(sm[0][t], sm[1][t]), f4add(sm[2][t], sm[3][t]));
        ((float4*)(partial + (size_t)bid * DIM))[t] = r;
    }
}

// ---------------------------------------------------------------------------
// K2: reduce partials -> means, bias GEMVs, WT fold, M bound.
// blocks [0,256): pair p. blocks 256,257: W[:D] -> bf16 W^T and M=sum|w|.
// Partials are L2/L3-hot (6.3 MB, just written).
// ---------------------------------------------------------------------------
__global__ __launch_bounds__(512) void k_redbias(
    const float* __restrict__ partial,
    const float* __restrict__ W1, const float* __restrict__ W2,
    const float* __restrict__ w2v, const float* __restrict__ w1v,
    float* __restrict__ bias_e, float* __restrict__ bias_c,
    unsigned short* __restrict__ WT1, unsigned short* __restrict__ WT2,
    float* __restrict__ Mval)
{
    const int bid = blockIdx.x;
    const int t = threadIdx.x;
    __shared__ float msum[8];
    if (bid >= BE) {
        const int side = bid - BE;
        const float* W = side ? W2 : W1;
        unsigned short* WT = side ? WT2 : WT1;
        for (int i = t; i < OUTD * DIM; i += 512) {
            const int d = i & (DIM - 1);
            const int n = i >> 8;
            BF1 c; c.h = __float2bfloat16(W[(size_t)d * OUTD + n]);
            WT[n * DIM + d] = c.u;
        }
        // M = sum |w| for this side's score vector (side0: w2, side1: w1)
        const float* wv_ = side ? w1v : w2v;
        float av = (t < OUTD) ? fabsf(wv_[t]) : 0.f;
#pragma unroll
        for (int off = 1; off < 64; off <<= 1) av += __shfl_xor(av, off, 64);
        if ((t & 63) == 0) msum[t >> 6] = av;
        __syncthreads();
        if (t == 0)
            Mval[side] = msum[0] + msum[1] + msum[2] + msum[3]
                       + msum[4] + msum[5] + msum[6] + msum[7];
        return;
    }
    const int pair = bid;
    __shared__ float mc[DIM], me[DIM];
    __shared__ float sb[2][2][OUTD];
    const float* pb = partial + (size_t)pair * NCHP * DIM;
    if (t < 256) {                 // claim mean: chunks 16..23
        float s = 0.f;
#pragma unroll
        for (int j = 0; j < NCH_CL; ++j) s += pb[(NCH_EV + j) * DIM + t];
        mc[t] = s * (1.f / LCL);
    } else {                       // evidence mean: chunks 0..15
        const int t2 = t - 256;
        float s = 0.f;
#pragma unroll
        for (int j = 0; j < NCH_EV; ++j) s += pb[j * DIM + t2];
        me[t2] = s * (1.f / LEV);
    }
    __syncthreads();
    // side 0: claim-mean @ W1[D:] -> bias_e ; side 1: evid-mean @ W2[D:] -> bias_c
    const int side = t >> 8, o = t & 127, dh = (t >> 7) & 1;
    const float* W = side ? W2 : W1;
    const float* m = side ? me : mc;
    float s = 0.f;
#pragma unroll 8
    for (int i = 0; i < 128; ++i) {
        const int d = dh * 128 + i;
        s += m[d] * W[(size_t)(DIM + d) * OUTD + o];
    }
    sb[side][dh][o] = s;
    __syncthreads();
    if (t < 256) {
        const int sd = t >> 7, oo = t & 127;
        const float bv = sb[sd][0][oo] + sb[sd][1][oo];
        (sd ? bias_c : bias_e)[pair * OUTD + oo] = bv;
    }
}

// ---------------------------------------------------------------------------
// K3: fully parallel partials (verified in R7, unchanged). One block per
// 32-row chunk of one (pair,side). Fixed-shift softmax e = exp(a - M)
// (M rigorous bound: |tanh|<1) makes chunk partials (O_part, l_part)
// directly summable. Data is L3-hot after k_meanpart.
// ---------------------------------------------------------------------------
__global__ __launch_bounds__(256, 2) void k_main(
    const float* __restrict__ claim, const float* __restrict__ evidence,
    const unsigned short* __restrict__ WT1, const unsigned short* __restrict__ WT2,
    const float* __restrict__ w2v, const float* __restrict__ w1v,
    const float* __restrict__ bias_e, const float* __restrict__ bias_c,
    const int* __restrict__ emask, const int* __restrict__ cmask,
    const float* __restrict__ Mval,
    float* __restrict__ O_part, float* __restrict__ l_part)
{
    constexpr int TR  = 32;                 // chunk rows
    constexpr int SR4 = 65;                 // row stride in float4 (pad between rows)
    __shared__ float4 sA4[TR * SR4];        // 33280 B
    __shared__ float sred[4][TR];

    const int bid = blockIdx.x;
    const int pair = bid / NCHP;
    const int c = bid - pair * NCHP;
    const bool is_ev = c < NCH_EV;
    const int chunk = is_ev ? c : c - NCH_EV;
    const float* __restrict__ seq  = is_ev ? evidence : claim;
    const unsigned short* __restrict__ WT = is_ev ? WT1 : WT2;
    const float* __restrict__ wvec = is_ev ? w2v : w1v;
    const float* __restrict__ bias = is_ev ? bias_e : bias_c;
    const int*   __restrict__ mask = is_ev ? emask : cmask;
    const int L = is_ev ? LEV : LCL;
    const float M = Mval[is_ev ? 0 : 1];

    const int t = threadIdx.x;
    const int lane = t & 63;
    const int wv = t >> 6;                  // 0..3 = col group (32 cols each)
    const int q = lane >> 4, c16 = lane & 15;

    float bc[2], wc[2];
#pragma unroll
    for (int ct = 0; ct < 2; ++ct) {
        const int col = wv * 32 + ct * 16 + c16;
        bc[ct] = bias[pair * OUTD + col];
        wc[ct] = wvec[col];
    }
    // preload B fragments (WT is L1/L2-hot: 64 KB shared by all blocks)
    bf16x8 breg[16];
#pragma unroll
    for (int ks = 0; ks < 8; ++ks)
#pragma unroll
        for (int ct = 0; ct < 2; ++ct)
            breg[ks * 2 + ct] = *(const bf16x8*)(
                WT + (size_t)(wv * 32 + ct * 16 + c16) * DIM + ks * 32 + q * 8);

    // ---- stage this 32x256 fp32 chunk: wave wv DMAs rows wv*8..+8 ----
    const float4* base = (const float4*)(seq + ((size_t)pair * L + chunk * TR) * DIM);
#pragma unroll
    for (int j = 0; j < 8; ++j) {
        const int row = wv * 8 + j;
        gl_lds16(base + row * 64 + lane, &sA4[row * SR4]);
    }
    const int mk = mask[pair * L + chunk * TR + (lane & 31)];
    __syncthreads();                        // drains DMA (vmcnt0+lgkm0+barrier)

    // ---- MFMA scores: rows 0..32, cols wv*32..+32 (verified mapping) ----
    floatx4 acc[2][2];
    acc[0][0] = (floatx4){0.f, 0.f, 0.f, 0.f};
    acc[0][1] = (floatx4){0.f, 0.f, 0.f, 0.f};
    acc[1][0] = (floatx4){0.f, 0.f, 0.f, 0.f};
    acc[1][1] = (floatx4){0.f, 0.f, 0.f, 0.f};
#pragma unroll
    for (int ks = 0; ks < 8; ++ks) {
#pragma unroll
        for (int ra = 0; ra < 2; ++ra) {
            const float4 lo = sA4[(ra * 16 + c16) * SR4 + ks * 8 + q * 2];
            const float4 hi = sA4[(ra * 16 + c16) * SR4 + ks * 8 + q * 2 + 1];
            union { bf16x8 v; BF2 p[4]; } ua;
            ua.p[0].h = __float22bfloat162_rn(make_float2(lo.x, lo.y));
            ua.p[1].h = __float22bfloat162_rn(make_float2(lo.z, lo.w));
            ua.p[2].h = __float22bfloat162_rn(make_float2(hi.x, hi.y));
            ua.p[3].h = __float22bfloat162_rn(make_float2(hi.z, hi.w));
#pragma unroll
            for (int ct = 0; ct < 2; ++ct)
                acc[ra][ct] = __builtin_amdgcn_mfma_f32_16x16x32_bf16(
                    ua.v, breg[ks * 2 + ct], acc[ra][ct], 0, 0, 0);
        }
    }

    // ---- tanh-dot epilogue -> sred[colgroup][row] ----
#pragma unroll
    for (int ra = 0; ra < 2; ++ra) {
#pragma unroll
        for (int reg = 0; reg < 4; ++reg) {
            float s = fast_tanh(acc[ra][0][reg] + bc[0]) * wc[0]
                    + fast_tanh(acc[ra][1][reg] + bc[1]) * wc[1];
#pragma unroll
            for (int off = 1; off < 16; off <<= 1) s += __shfl_xor(s, off, 64);
            if (c16 == 0)
                sred[wv][ra * 16 + q * 4 + reg] = s;
        }
    }
    __syncthreads();

    // ---- fixed-shift softmax numerators: 1 row per lane (duplicated halves) ----
    const int r31 = lane & 31;
    const float a = sred[0][r31] + sred[1][r31] + sred[2][r31] + sred[3][r31];
    const float e = mk ? __expf(a - M) : 0.f;
    float sl = e;                           // chunk l: sum rows 0..31 (within halves)
#pragma unroll
    for (int off = 1; off < 32; off <<= 1) sl += __shfl_xor(sl, off, 64);

    // ---- weighted sum from LDS fp32: wave wv covers rows wv*8..+8 ----
    float4 Oac = make_float4(0.f, 0.f, 0.f, 0.f);
#pragma unroll
    for (int r = 0; r < 8; ++r) {
        const int rw = wv * 8 + r;
        const float pl = __shfl(e, rw, 64);
        const float4 v = sA4[rw * SR4 + lane];
        Oac.x += pl * v.x; Oac.y += pl * v.y; Oac.z += pl * v.z; Oac.w += pl * v.w;
    }

    // ---- cross-wave reduce (reuse sA4) and write partial ----
    __syncthreads();
    ((float4*)sA4)[t] = Oac;
    __syncthreads();
    if (t < 64) {
        float4 s = make_float4(0.f, 0.f, 0.f, 0.f);
#pragma unroll
        for (int j = 0; j < 4; ++j) {
            const float4 v = ((float4*)sA4)[j * 64 + t];
            s.x += v.x; s.y += v.y; s.z += v.z; s.w += v.w;
        }
        ((float4*)(O_part + (size_t)bid * DIM))[t] = s;
    }
    if (t == 0) l_part[bid] = sl;
}

// ---------------------------------------------------------------------------
// K4: combine chunk partials and normalize. One block per (pair,side).
// even bid = evidence -> e_hat (out + BE*DIM); odd = claim -> c_hat (out).
// ---------------------------------------------------------------------------
__global__ __launch_bounds__(64) void k_combine(
    const float* __restrict__ O_part, const float* __restrict__ l_part,
    float* __restrict__ out)
{
    const int bid = blockIdx.x;
    const int t = threadIdx.x;
    const bool is_ev = (bid & 1) == 0;
    const int pair = bid >> 1;
    const int base = pair * NCHP + (is_ev ? 0 : NCH_EV);
    const int NC = is_ev ? NCH_EV : NCH_CL;
    float* __restrict__ outp = is_ev ? out + (size_t)BE * DIM : out;

    float4 s = make_float4(0.f, 0.f, 0.f, 0.f);
    float l = 0.f;
    for (int i = 0; i < NC; ++i) {
        const float4 v = ((const float4*)(O_part + (size_t)(base + i) * DIM))[t];
        s.x += v.x; s.y += v.y; s.z += v.z; s.w += v.w;
        l += l_part[base + i];
    }
    const float inv = 1.f / l;
    ((float4*)(outp + (size_t)pair * DIM))[t] =
        make_float4(s.x * inv, s.y * inv, s.z * inv, s.w * inv);
}

// ---------------------------------------------------------------------------
extern "C" void kernel_launch(void* const* d_in, const int* in_sizes, int n_in,
                              void* d_out, int out_size, void* d_ws, size_t ws_size,
                              hipStream_t stream) {
    const float* claim    = (const float*)d_in[0];
    const int*   cmask    = (const int*)  d_in[1];
    const float* evidence = (const float*)d_in[2];
    const int*   emask    = (const int*)  d_in[3];
    const float* W1       = (const float*)d_in[4];
    const float* w2       = (const float*)d_in[5];
    const float* W2       = (const float*)d_in[6];
    const float* w1       = (const float*)d_in[7];
    float* out = (float*)d_out;

    // Workspace (R7-proven footprint, ~6.5 MB): `buf` serves as `partial`
    // (k_meanpart -> k_redbias) then as `O_part` (k_main -> k_combine).
    // Live ranges are disjoint; same-stream kernels serialize.
    float* ws = (float*)d_ws;
    float* bias_e = ws;                               // 256*128
    float* bias_c = bias_e + BE * OUTD;               // 256*128
    float* buf    = bias_c + BE * OUTD;               // 6144*256 (aliased)
    float* l_part = buf + (size_t)NBLK * DIM;         // 6144
    float* Mval   = l_part + NBLK;                    // 2
    unsigned short* WT1 = (unsigned short*)(Mval + 2);
    unsigned short* WT2 = WT1 + OUTD * DIM;

    k_meanpart<<<NBLK, 256, 0, stream>>>(claim, evidence, buf);
    k_redbias<<<BE + 2, 512, 0, stream>>>(buf, W1, W2, w2, w1,
                                          bias_e, bias_c, WT1, WT2, Mval);
    k_main<<<NBLK, 256, 0, stream>>>(claim, evidence, WT1, WT2, w2, w1,
                                     bias_e, bias_c, emask, cmask, Mval,
                                     buf, l_part);
    // output order: c_hat first (claim side), e_hat second (evidence side)
    k_combine<<<2 * BE, 64, 0, stream>>>(buf, l_part, out);
}